// Round 4
// baseline (88.144 us; speedup 1.0000x reference)
//
#include <hip/hip_runtime.h>

typedef short short8 __attribute__((ext_vector_type(8)));
typedef float floatx16 __attribute__((ext_vector_type(16)));

#define B_    4
#define NPTS  8192           // N == M == 8192
#define ITB   128            // i per block (4 waves x 32)
#define ISPL  (NPTS / ITB)   // 64 i-splits
#define JCH   1024           // j per staged chunk
#define NCH   (NPTS / JCH)   // 8 chunks
#define NJT   (JCH / 32)     // 32 mfma per chunk per wave
#define TOT   (B_ * NPTS)    // 32768
#define ARR   32768          // granules per packed array (B_*NPTS)

// ws layout: 8 granule arrays of short8[ARR] (16 B each, 4 MB total):
//   [0] A0 dir0 = pack_dst(gt) k0..7     [1] A1 dir0 = pack_dst(gt) k8..15
//   [2] A0 dir1 = pack_dst(pred)         [3] A1 dir1 = pack_dst(pred)
//   [4] B0 dir0 = pack_src(pred)         [5] B1 dir0 = pack_src(pred)
//   [6] B0 dir1 = pack_src(gt)           [7] B1 dir1 = pack_src(gt)
// Re-written fully by pack_kernel every iteration (ws is poisoned per iter).

__device__ __forceinline__ unsigned short bf16h(float v) {
  unsigned u = __float_as_uint(v);
  return (unsigned short)((u + 0x7FFFu + ((u >> 16) & 1u)) >> 16);   // RNE
}
__device__ __forceinline__ void bf16split(float v, unsigned short& h, unsigned short& l) {
  h = bf16h(v);
  l = bf16h(v - __uint_as_float((unsigned)h << 16));
}

// K-slot scheme (k0..15, all real) — byte-identical to the R3-proven kernel:
//   A (dst j): k0..7  [axh axh axl axl  ayh ayh ayl ayl]      a = -2g
//              k8..15 [azh azh azl azl  wh  wl  1   1 ]       w = ||g||^2
//   B (src i): k0..7  [pxh pxl pxh pxl  pyh pyl pyh pyl]
//              k8..15 [pzh pzl pzh pzl  1   1   qh  ql]       q = ||p||^2
// Sum_k A[j][k]B[k][i] = -2<g,p> + ||g||^2 + ||p||^2 = squared distance.
__device__ __forceinline__ void pack_dst(const float* g, short8& s0, short8& s1) {
  const float x = g[0], y = g[1], z = g[2];
  const float w = fmaf(x, x, fmaf(y, y, z * z));
  unsigned short xh, xl, yh, yl, zh, zl, wh, wl;
  bf16split(-2.f * x, xh, xl); bf16split(-2.f * y, yh, yl);
  bf16split(-2.f * z, zh, zl); bf16split(w, wh, wl);
  s0 = (short8){(short)xh,(short)xh,(short)xl,(short)xl,
                (short)yh,(short)yh,(short)yl,(short)yl};
  s1 = (short8){(short)zh,(short)zh,(short)zl,(short)zl,
                (short)wh,(short)wl,(short)0x3F80,(short)0x3F80};
}
__device__ __forceinline__ void pack_src(const float* p, short8& s0, short8& s1) {
  const float x = p[0], y = p[1], z = p[2];
  const float qq = fmaf(x, x, fmaf(y, y, z * z));
  unsigned short xh, xl, yh, yl, zh, zl, qh, ql;
  bf16split(x, xh, xl); bf16split(y, yh, yl);
  bf16split(z, zh, zl); bf16split(qq, qh, ql);
  s0 = (short8){(short)xh,(short)xl,(short)xh,(short)xl,
                (short)yh,(short)yl,(short)yh,(short)yl};
  s1 = (short8){(short)zh,(short)zl,(short)zh,(short)zl,
                (short)0x3F80,(short)0x3F80,(short)qh,(short)ql};
}

// Pack every point once (removes 16x redundant packing from the hot kernel).
// 65536 points; gid>>15 selects cloud (0=pred, 1=gt).
__global__ __launch_bounds__(256) void pack_kernel(
    const float* __restrict__ pred, const float* __restrict__ gt,
    short8* __restrict__ W) {
  const int gid = blockIdx.x * 256 + threadIdx.x;
  const int cloud = gid >> 15;
  const int idx = gid & (ARR - 1);            // b*NPTS + pt
  const float* p = (cloud ? gt : pred) + (size_t)idx * 3;
  short8 d0, d1, s0, s1;
  pack_dst(p, d0, d1);
  pack_src(p, s0, s1);
  if (cloud) {  // gt: dst for dir0, src for dir1
    W[0 * ARR + idx] = d0;  W[1 * ARR + idx] = d1;
    W[6 * ARR + idx] = s0;  W[7 * ARR + idx] = s1;
  } else {      // pred: dst for dir1, src for dir0
    W[2 * ARR + idx] = d0;  W[3 * ARR + idx] = d1;
    W[4 * ARR + idx] = s0;  W[5 * ARR + idx] = s1;
  }
}

// grid (ISPL, 2*B_) = (64,8) = 512 blocks, 256 thr (4 waves).
// Block owns 128 i over ALL 8192 j -> per-i min completes in-register:
// no slots buffer, no atomicMin, no pass2. One atomicAdd(out) per block.
// mfma_f32_32x32x16_bf16 mapping (R3-proven):
//   A[row=j][k], B[k][col=i]; lane: n=lane&31 (point), h=lane>>5 (k-half);
//   D: col=lane&31, row=(reg&3)+8*(reg>>2)+4*(lane>>5).
// NO inline asm on MFMA outputs (R1/R2 lesson); nested fminf fuses to min3.
__global__ __launch_bounds__(256, 2) void chamfer_main(
    const short8* __restrict__ W, float* __restrict__ out) {
  __shared__ short8 ldsA[2 * JCH];   // [A0: JCH][A1: JCH] = 32 KB
  __shared__ short8 ldsB[256];       // [B0: 128][B1: 128] = 4 KB
  __shared__ float wsum[4];

  const int zb  = blockIdx.y;
  const int dir = zb >> 2;
  const int b   = zb & 3;
  const int tid  = threadIdx.x;
  const int lane = tid & 63;
  const int w    = tid >> 6;
  const int ibase = blockIdx.x * ITB;
  const size_t boff = (size_t)b * NPTS;

  const short8* A0 = W + (size_t)(dir ? 2 : 0) * ARR + boff;
  const short8* A1 = W + (size_t)(dir ? 3 : 1) * ARR + boff;
  const short8* S0 = W + (size_t)(dir ? 6 : 4) * ARR + boff;
  const short8* S1 = W + (size_t)(dir ? 7 : 5) * ARR + boff;

  // Stage B once: 128 i-points x 2 k-halves (coalesced 16 B granules).
  ldsB[tid] = (tid < 128) ? S0[ibase + tid] : S1[ibase + tid - 128];

  // Prefetch chunk 0 A-granules into regs (T14 issue-early).
  short8 pre[8];
#pragma unroll
  for (int k = 0; k < 8; ++k) {
    const int g = tid + k * 256;
    pre[k] = (g < JCH) ? A0[g] : A1[g - JCH];
  }

  __syncthreads();                      // ldsB visible
  const int n = lane & 31;
  const int h = lane >> 5;
  const short8 bf = ldsB[h * 128 + w * 32 + n];
  const int abase = h * JCH + n;

  float ma = 1e30f, mb = 1e30f;
  const floatx16 zero16 = {0.f,0.f,0.f,0.f, 0.f,0.f,0.f,0.f,
                           0.f,0.f,0.f,0.f, 0.f,0.f,0.f,0.f};

  for (int c = 0; c < NCH; ++c) {
    __syncthreads();                    // prev compute done -> ldsA writable
#pragma unroll
    for (int k = 0; k < 8; ++k) ldsA[tid + k * 256] = pre[k];
    __syncthreads();
    if (c + 1 < NCH) {                  // issue next chunk's loads early;
      const size_t cb = (size_t)(c + 1) * JCH;   // latency hides under MFMAs
#pragma unroll
      for (int k = 0; k < 8; ++k) {
        const int g = tid + k * 256;
        pre[k] = (g < JCH) ? A0[cb + g] : A1[cb + g - JCH];
      }
    }
#pragma unroll 8
    for (int jt = 0; jt < NJT; ++jt) {
      const short8 af = ldsA[abase + jt * 32];
      floatx16 d = __builtin_amdgcn_mfma_f32_32x32x16_bf16(af, bf, zero16, 0, 0, 0);
      float ca = fminf(fminf(d[0], d[1]), d[2]);
      ca = fminf(fminf(ca, d[3]), d[4]);
      ca = fminf(fminf(ca, d[5]), d[6]);
      ma = fminf(fminf(ca, d[7]), ma);
      float cb2 = fminf(fminf(d[8], d[9]), d[10]);
      cb2 = fminf(fminf(cb2, d[11]), d[12]);
      cb2 = fminf(fminf(cb2, d[13]), d[14]);
      mb = fminf(fminf(cb2, d[15]), mb);
    }
  }

  // Merge k-halves (lanes n, n+32 hold complementary j-rows of col i=n),
  // then wave-sum the 32 per-i mins (xor offsets <32 stay in-half).
  const float m = fminf(ma, mb);
  float v = fminf(m, __shfl_xor(m, 32));
  v += __shfl_xor(v, 1);
  v += __shfl_xor(v, 2);
  v += __shfl_xor(v, 4);
  v += __shfl_xor(v, 8);
  v += __shfl_xor(v, 16);
  if (lane == 0) wsum[w] = v;
  __syncthreads();
  if (tid == 0)
    atomicAdd(out, (wsum[0] + wsum[1] + wsum[2] + wsum[3]) * (1.0f / TOT));
}

extern "C" void kernel_launch(void* const* d_in, const int* in_sizes, int n_in,
                              void* d_out, int out_size, void* d_ws, size_t ws_size,
                              hipStream_t stream) {
  const float* pred = (const float*)d_in[0];
  const float* gt   = (const float*)d_in[1];
  short8* W  = (short8*)d_ws;
  float* out = (float*)d_out;

  hipMemsetAsync(out, 0, out_size * sizeof(float), stream);
  pack_kernel<<<(2 * ARR) / 256, 256, 0, stream>>>(pred, gt, W);
  chamfer_main<<<dim3(ISPL, 2 * B_), 256, 0, stream>>>(W, out);
}

// Round 6
// 76.468 us; speedup vs baseline: 1.1527x; 1.1527x over previous
//
#include <hip/hip_runtime.h>

typedef short short8 __attribute__((ext_vector_type(8)));
typedef float floatx16 __attribute__((ext_vector_type(16)));

#define B_    4
#define NPTS  8192           // N == M == 8192
#define IS    16             // i-splits (512 src per block)
#define JS    16             // j-splits (512 dst per block)
#define ITB   512
#define JTB   512
#define NT    4              // i-tiles (32 wide) per wave -> 128 i/wave
#define NJT   16             // j-tiles (32 wide) per block
#define TOT   (B_ * NPTS)    // 32768
#define ARR   32768          // granules per packed array (B_*NPTS)

// ws layout (R4-proven pack): 8 granule arrays short8[ARR] (4 MB), then
// slots uint32[2*TOT] (256 KiB) at offset 8*ARR granules.
//   [0][1] A k0..7/k8..15 dir0 = pack_dst(gt)    [2][3] dir1 = pack_dst(pred)
//   [4][5] B k0..7/k8..15 dir0 = pack_src(pred)  [6][7] dir1 = pack_src(gt)
// A-array index = dir*2 + h;  B-array index = 4 + dir*2 + h.

__device__ __forceinline__ unsigned short bf16h(float v) {
  unsigned u = __float_as_uint(v);
  return (unsigned short)((u + 0x7FFFu + ((u >> 16) & 1u)) >> 16);   // RNE
}
__device__ __forceinline__ void bf16split(float v, unsigned short& h, unsigned short& l) {
  h = bf16h(v);
  l = bf16h(v - __uint_as_float((unsigned)h << 16));
}

// K-slot scheme (k0..15, all real) — byte-identical to R3/R4-proven:
//   A (dst j): k0..7  [axh axh axl axl  ayh ayh ayl ayl]      a = -2g
//              k8..15 [azh azh azl azl  wh  wl  1   1 ]       w = ||g||^2
//   B (src i): k0..7  [pxh pxl pxh pxl  pyh pyl pyh pyl]
//              k8..15 [pzh pzl pzh pzl  1   1   qh  ql]       q = ||p||^2
// Sum_k A[j][k]B[k][i] = -2<g,p> + ||g||^2 + ||p||^2 = squared distance.
__device__ __forceinline__ void pack_dst(const float* g, short8& s0, short8& s1) {
  const float x = g[0], y = g[1], z = g[2];
  const float w = fmaf(x, x, fmaf(y, y, z * z));
  unsigned short xh, xl, yh, yl, zh, zl, wh, wl;
  bf16split(-2.f * x, xh, xl); bf16split(-2.f * y, yh, yl);
  bf16split(-2.f * z, zh, zl); bf16split(w, wh, wl);
  s0 = (short8){(short)xh,(short)xh,(short)xl,(short)xl,
                (short)yh,(short)yh,(short)yl,(short)yl};
  s1 = (short8){(short)zh,(short)zh,(short)zl,(short)zl,
                (short)wh,(short)wl,(short)0x3F80,(short)0x3F80};
}
__device__ __forceinline__ void pack_src(const float* p, short8& s0, short8& s1) {
  const float x = p[0], y = p[1], z = p[2];
  const float qq = fmaf(x, x, fmaf(y, y, z * z));
  unsigned short xh, xl, yh, yl, zh, zl, qh, ql;
  bf16split(x, xh, xl); bf16split(y, yh, yl);
  bf16split(z, zh, zl); bf16split(qq, qh, ql);
  s0 = (short8){(short)xh,(short)xl,(short)xh,(short)xl,
                (short)yh,(short)yl,(short)yh,(short)yl};
  s1 = (short8){(short)zh,(short)zl,(short)zh,(short)zl,
                (short)0x3F80,(short)0x3F80,(short)qh,(short)ql};
}

// Pack every point once (R4-proven) + init slots (1:1 thread:slot) + out=0.
// Later kernels consume these -> ordering guaranteed by stream serialization.
__global__ __launch_bounds__(256) void pack_kernel(
    const float* __restrict__ pred, const float* __restrict__ gt,
    short8* __restrict__ W, unsigned* __restrict__ slots,
    float* __restrict__ out) {
  const int gid = blockIdx.x * 256 + threadIdx.x;   // 65536 threads
  slots[gid] = 0xFFFFFFFFu;
  if (gid == 0) out[0] = 0.f;
  const int cloud = gid >> 15;
  const int idx = gid & (ARR - 1);                  // b*NPTS + pt
  const float* p = (cloud ? gt : pred) + (size_t)idx * 3;
  short8 d0, d1, s0, s1;
  pack_dst(p, d0, d1);
  pack_src(p, s0, s1);
  if (cloud) {  // gt: dst for dir0, src for dir1
    W[0 * ARR + idx] = d0;  W[1 * ARR + idx] = d1;
    W[6 * ARR + idx] = s0;  W[7 * ARR + idx] = s1;
  } else {      // pred: dst for dir1, src for dir0
    W[2 * ARR + idx] = d0;  W[3 * ARR + idx] = d1;
    W[4 * ARR + idx] = s0;  W[5 * ARR + idx] = s1;
  }
}

// grid (IS, JS, 2*B_) = (16,16,8) = 2048 blocks, 256 thr (4 waves) — R3's
// proven parallelism (8 waves/SIMD sequential TLP). With pre-packed W, each
// lane loads its MFMA fragment DIRECTLY from global: no LDS, no barriers,
// no pack in the hot kernel. af addresses are identical across the 4 waves
// (L1-served after first touch; per-(dir,b) A-stream is 256 KB, L2-resident).
// mfma_f32_32x32x16_bf16 mapping (R3-proven):
//   A[row=j][k], B[k][col=i]; lane: n=lane&31 (point), h=lane>>5 (k-half);
//   D: col=lane&31, row=(reg&3)+8*(reg>>2)+4*(lane>>5).
// NO inline asm on MFMA outputs (R1/R2 lesson); nested fminf fuses to min3.
__global__ __launch_bounds__(256, 4) void mfma_pass_kernel(
    const short8* __restrict__ W, unsigned* __restrict__ slots) {
  const int zb  = blockIdx.z;
  const int dir = zb >> 2;
  const int b   = zb & 3;
  const int tid   = threadIdx.x;
  const int lane  = tid & 63;
  const int w     = tid >> 6;
  const int n     = lane & 31;   // point index within 32-tile (A: j, B: i)
  const int h     = lane >> 5;   // k-half: 0 -> k0..7, 1 -> k8..15
  const int jbase = blockIdx.y * JTB;
  const int ibase = blockIdx.x * ITB;

  const short8* Ap = W + (size_t)(dir * 2 + h) * ARR + (size_t)b * NPTS + jbase;
  const short8* Bp = W + (size_t)(4 + dir * 2 + h) * ARR + (size_t)b * NPTS + ibase;

  // B fragments: one direct load each (32 lanes x 16 B contiguous per half).
  short8 bf[NT];
  float  ma[NT], mb[NT];         // two independent min chains per tile
#pragma unroll
  for (int t = 0; t < NT; ++t) {
    bf[t] = Bp[w * 128 + t * 32 + n];
    ma[t] = 1e30f;
    mb[t] = 1e30f;
  }

  const floatx16 zero16 = {0.f,0.f,0.f,0.f, 0.f,0.f,0.f,0.f,
                           0.f,0.f,0.f,0.f, 0.f,0.f,0.f,0.f};

#pragma unroll 4
  for (int jt = 0; jt < NJT; ++jt) {
    const short8 af = Ap[jt * 32 + n];
#pragma unroll
    for (int t = 0; t < NT; ++t) {
      floatx16 d = __builtin_amdgcn_mfma_f32_32x32x16_bf16(af, bf[t], zero16, 0, 0, 0);
      // Two independent 8-value chains; min(min(a,b),c) nests fuse to min3.
      float ca = fminf(fminf(d[0], d[1]), d[2]);
      ca = fminf(fminf(ca, d[3]), d[4]);
      ca = fminf(fminf(ca, d[5]), d[6]);
      ma[t] = fminf(fminf(ca, d[7]), ma[t]);
      float cb = fminf(fminf(d[8], d[9]), d[10]);
      cb = fminf(fminf(cb, d[11]), d[12]);
      cb = fminf(fminf(cb, d[13]), d[14]);
      mb[t] = fminf(fminf(cb, d[15]), mb[t]);
    }
  }

  // Merge the two k-halves (lanes n, n+32 hold complementary j-rows of the
  // same column i=n), then ONE atomicMin per (i, block).  (R3-proven)
#pragma unroll
  for (int t = 0; t < NT; ++t) {
    float v = fminf(ma[t], mb[t]);
    v = fminf(v, __shfl_xor(v, 32));
    if (lane < 32) {
      const int gi = ibase + w * 128 + t * 32 + lane;
      const int bi = __float_as_int(v);
      const unsigned u = (unsigned)bi ^ (unsigned)((bi >> 31) | 0x80000000);
      atomicMin(&slots[(size_t)(dir * B_ + b) * NPTS + gi], u);
    }
  }
}

// Sweep 2*TOT slots, decode, reduce, one atomic per block.  (R3-proven)
__global__ __launch_bounds__(256) void pass2_kernel(
    const unsigned* __restrict__ slots, float* __restrict__ out) {
  const int gid = blockIdx.x * 256 + threadIdx.x;   // 8192 threads
  float s = 0.f;
#pragma unroll
  for (int k = 0; k < 8; ++k) {
    const unsigned u = slots[gid + k * 8192];
    const int bi = (u & 0x80000000u) ? (int)(u ^ 0x80000000u) : (int)~u;
    s += __int_as_float(bi);
  }
  __shared__ float red[256];
  const int tid = threadIdx.x;
  red[tid] = s;
  __syncthreads();
  for (int st = 128; st > 0; st >>= 1) {
    if (tid < st) red[tid] += red[tid + st];
    __syncthreads();
  }
  if (tid == 0) atomicAdd(out, red[0] * (1.0f / TOT));
}

extern "C" void kernel_launch(void* const* d_in, const int* in_sizes, int n_in,
                              void* d_out, int out_size, void* d_ws, size_t ws_size,
                              hipStream_t stream) {
  const float* pred = (const float*)d_in[0];
  const float* gt   = (const float*)d_in[1];
  short8* W = (short8*)d_ws;
  unsigned* slots = (unsigned*)(W + 8 * ARR);       // offset 4 MB, 256 KiB
  float* out = (float*)d_out;

  pack_kernel<<<(2 * ARR) / 256, 256, 0, stream>>>(pred, gt, W, slots, out);
  mfma_pass_kernel<<<dim3(IS, JS, 2 * B_), 256, 0, stream>>>(W, slots);
  pass2_kernel<<<(2 * TOT) / (256 * 8), 256, 0, stream>>>(slots, out);
}